// Round 3
// baseline (152.700 us; speedup 1.0000x reference)
//
#include <hip/hip_runtime.h>
#include <hip/hip_bf16.h>
#include <stdint.h>

typedef __attribute__((ext_vector_type(8))) short short8;
typedef __attribute__((ext_vector_type(4))) short short4_t;
typedef __attribute__((ext_vector_type(4))) float f32x4;
typedef __attribute__((ext_vector_type(2))) unsigned int u32x2;
typedef __attribute__((ext_vector_type(4))) unsigned int u32x4;

union FragU { u32x4 u; short8 s; };
union Frag2U { u32x2 u; short4_t s; };

__device__ __forceinline__ unsigned short f2bf(float f) {
  union { float f; uint32_t u; } v; v.f = f;
  uint32_t u = v.u;
  return (unsigned short)((u + 0x7FFFu + ((u >> 16) & 1u)) >> 16);
}

__device__ __forceinline__ unsigned pk2(float a, float b) {
  return (unsigned)f2bf(a) | ((unsigned)f2bf(b) << 16);
}

__device__ __forceinline__ void gload_lds16(const void* g, void* l) {
  __builtin_amdgcn_global_load_lds(
      (const __attribute__((address_space(1))) unsigned int*)g,
      (__attribute__((address_space(3))) unsigned int*)l, 16, 0, 0);
}

// 16x16x16 bf16 MFMA: prefer builtin (compiler handles MFMA hazards);
// fallback inline asm with conservative s_nop guards.
#if defined(__has_builtin)
#if __has_builtin(__builtin_amdgcn_mfma_f32_16x16x16bf16_1k)
#define HAVE_MFMA16_BUILTIN 1
#endif
#endif

__device__ __forceinline__ f32x4 mfma16(u32x2 a, u32x2 b, f32x4 c) {
#ifdef HAVE_MFMA16_BUILTIN
  Frag2U ua, ub;
  ua.u = a; ub.u = b;
  return __builtin_amdgcn_mfma_f32_16x16x16bf16_1k(ua.s, ub.s, c, 0, 0, 0);
#else
  asm volatile("s_nop 1\n\t"
               "v_mfma_f32_16x16x16_bf16 %0, %1, %2, %0\n\t"
               "s_nop 7\n\t"
               "s_nop 7"
               : "+v"(c) : "v"(a), "v"(b));
  return c;
#endif
}

// ---------------- K1a: per-column partial sums over 64-row chunks ----------------
__global__ __launch_bounds__(256) void k_stats(const float* __restrict__ x,
                                               float* __restrict__ psum,
                                               float* __restrict__ psq) {
  int t = threadIdx.x;
  int cb = blockIdx.x & 3;    // 4 col blocks of 1024
  int ck = blockIdx.x >> 2;   // 64 row chunks of 64
  int c0 = cb * 1024 + t * 4;
  f32x4 s = {0.f, 0.f, 0.f, 0.f}, q = {0.f, 0.f, 0.f, 0.f};
  const float* base = x + (size_t)ck * 64 * 4096 + c0;
#pragma unroll 4
  for (int r = 0; r < 64; ++r) {
    f32x4 v = *(const f32x4*)(base + (size_t)r * 4096);
    s += v;
    q += v * v;
  }
  *(f32x4*)(psum + (size_t)ck * 4096 + c0) = s;
  *(f32x4*)(psq + (size_t)ck * 4096 + c0) = q;
}

// ---------------- K1b: finalize BN -> fused scale/shift coeffs ----------------
__global__ __launch_bounds__(256) void k_finalize(const float* __restrict__ psum,
                                                  const float* __restrict__ psq,
                                                  const float* __restrict__ gamma,
                                                  const float* __restrict__ beta,
                                                  float* __restrict__ An,
                                                  float* __restrict__ Bn) {
  int c = blockIdx.x * 256 + threadIdx.x;
  float s = 0.f, q = 0.f;
  for (int k = 0; k < 64; ++k) {
    s += psum[k * 4096 + c];
    q += psq[k * 4096 + c];
  }
  float mean = s * (1.0f / 4096.0f);
  float var = q * (1.0f / 4096.0f) - mean * mean;
  float a = gamma[c] * rsqrtf(var + 1e-5f);
  An[c] = a;
  Bn[c] = beta[c] - mean * a;
}

// ---------------- K2: Xn[65536,256] @ W^T (+bias) -> Qt,Kt (transposed [b][e][p]) and V (natural) ----------------
__global__ __launch_bounds__(256) void k_qkv(
    const float* __restrict__ x, const float* __restrict__ An, const float* __restrict__ Bn,
    const float* __restrict__ WQ, const float* __restrict__ bQ,
    const float* __restrict__ WK, const float* __restrict__ bK,
    const float* __restrict__ WV, const float* __restrict__ bV,
    unsigned short* __restrict__ Qt, unsigned short* __restrict__ Kt,
    unsigned short* __restrict__ Vo) {
  __shared__ unsigned short Asm[128 * 256];
  __shared__ unsigned short Bsm[128 * 256];
  int t = threadIdx.x;
  int mb = blockIdx.x >> 1, nb = blockIdx.x & 1;

  // stage A (normalize + bf16) once
  for (int i = 0; i < 16; ++i) {
    int m = i * 8 + (t >> 5);
    int k0 = (t & 31) * 8;
    size_t r = (size_t)(mb * 128 + m);
    const float* xs = x + r * 256 + k0;  // Xn flat == x flat
    f32x4 v0 = *(const f32x4*)(xs), v1 = *(const f32x4*)(xs + 4);
    int c = ((int)(r & 15)) * 256 + k0;
    f32x4 a0 = *(const f32x4*)(An + c), a1 = *(const f32x4*)(An + c + 4);
    f32x4 b0 = *(const f32x4*)(Bn + c), b1 = *(const f32x4*)(Bn + c + 4);
    f32x4 n0 = v0 * a0 + b0, n1 = v1 * a1 + b1;
    union { u32x4 u; unsigned short h[8]; } pk;
    pk.h[0] = f2bf(n0.x); pk.h[1] = f2bf(n0.y); pk.h[2] = f2bf(n0.z); pk.h[3] = f2bf(n0.w);
    pk.h[4] = f2bf(n1.x); pk.h[5] = f2bf(n1.y); pk.h[6] = f2bf(n1.z); pk.h[7] = f2bf(n1.w);
    int off = m * 512 + ((k0 * 2) ^ ((m & 7) << 4));
    *(u32x4*)((char*)Asm + off) = pk.u;
  }

  int w = t >> 6, ln = t & 63, lr = ln & 15, g = ln >> 4;
  int wm = (w >> 1) * 64, wn = (w & 1) * 64;

#pragma unroll
  for (int mat = 0; mat < 3; ++mat) {
    const float* W = (mat == 0) ? WQ : ((mat == 1) ? WK : WV);
    const float* bias = (mat == 0) ? bQ : ((mat == 1) ? bK : bV);
    unsigned short* Out = (mat == 0) ? Qt : ((mat == 1) ? Kt : Vo);
    float scale = (mat == 0) ? 0.0625f : 1.0f;  // fold 1/sqrt(d)=1/16 into Q (and its bias)

    __syncthreads();  // protect Bsm (and Asm on first iter) from prior reads
    for (int i = 0; i < 16; ++i) {
      int n = i * 8 + (t >> 5);
      int k0 = (t & 31) * 8;
      const float* wsrc = W + (size_t)(nb * 128 + n) * 256 + k0;
      f32x4 v0 = *(const f32x4*)(wsrc), v1 = *(const f32x4*)(wsrc + 4);
      union { u32x4 u; unsigned short h[8]; } pk;
      pk.h[0] = f2bf(v0.x); pk.h[1] = f2bf(v0.y); pk.h[2] = f2bf(v0.z); pk.h[3] = f2bf(v0.w);
      pk.h[4] = f2bf(v1.x); pk.h[5] = f2bf(v1.y); pk.h[6] = f2bf(v1.z); pk.h[7] = f2bf(v1.w);
      int off = n * 512 + ((k0 * 2) ^ ((n & 7) << 4));
      *(u32x4*)((char*)Bsm + off) = pk.u;
    }
    __syncthreads();

    f32x4 acc[4][4];
    f32x4 z4 = {0.f, 0.f, 0.f, 0.f};
#pragma unroll
    for (int a_ = 0; a_ < 4; ++a_)
#pragma unroll
      for (int b_ = 0; b_ < 4; ++b_) acc[a_][b_] = z4;

    for (int kk = 0; kk < 8; ++kk) {
      FragU af[4], bfr[4];
#pragma unroll
      for (int mt = 0; mt < 4; ++mt) {
        int m = wm + mt * 16 + lr;
        af[mt].u = *(const u32x4*)((const char*)Asm + m * 512 + ((kk * 64 + g * 16) ^ ((m & 7) << 4)));
      }
#pragma unroll
      for (int nt = 0; nt < 4; ++nt) {
        int n = wn + nt * 16 + lr;
        bfr[nt].u = *(const u32x4*)((const char*)Bsm + n * 512 + ((kk * 64 + g * 16) ^ ((n & 7) << 4)));
      }
#pragma unroll
      for (int mt = 0; mt < 4; ++mt)
#pragma unroll
        for (int nt = 0; nt < 4; ++nt)
          acc[mt][nt] = __builtin_amdgcn_mfma_f32_16x16x32_bf16(af[mt].s, bfr[nt].s, acc[mt][nt], 0, 0, 0);
    }

    // epilogue: C layout col=lane&15, row=(lane>>4)*4+reg (proven by this GEMM)
#pragma unroll
    for (int nt = 0; nt < 4; ++nt) {
      int ccol = nb * 128 + wn + nt * 16 + lr;
      float bv = bias[ccol];
#pragma unroll
      for (int mt = 0; mt < 4; ++mt) {
        int rbase = mb * 128 + wm + mt * 16;  // row = rbase + g*4+rg ; b = rbase>>4 uniform
        int b_ = rbase >> 4;
#pragma unroll
        for (int rg = 0; rg < 4; ++rg) {
          int p_ = g * 4 + rg;
          unsigned short val = f2bf((acc[mt][nt][rg] + bv) * scale);
          if (mat < 2) {
            Out[(size_t)b_ * 4096 + (size_t)ccol * 16 + p_] = val;  // transposed [b][e][p]
          } else {
            Out[(size_t)(rbase + p_) * 256 + ccol] = val;           // natural [b*16+p][e]
          }
        }
      }
    }
  }
}

// ---------------- K3: per-batch-row attention (all plain-layout, 16x16x16 MFMAs) ----------------
// LDS: Qt [e=256][p=16] (8KB) | Kt [f=256][p=16] (8KB) | V [p=16][f=256] swizzled (8KB)
#define LQT 0
#define LKT 8192
#define LVS 16384
#define LTOT 24576

__global__ __launch_bounds__(256, 3) void k_attn(
    const unsigned short* __restrict__ Qtg, const unsigned short* __restrict__ Ktg,
    const unsigned short* __restrict__ Vg, const float* __restrict__ x,
    float* __restrict__ out) {
  __shared__ char lds[LTOT];
  int b = blockIdx.x;
  int t = threadIdx.x;
  int w = t >> 6, ln = t & 63, lr = ln & 15, g = ln >> 4;

  // ---- stage: Qt,Kt linear copy; V with involution swizzle on source ----
  for (int i = w; i < 24; i += 4) {
    const unsigned short* srcmat;
    unsigned srcbyte;
    int region;
    if (i < 8) {
      srcmat = Qtg;
      srcbyte = (unsigned)b * 8192 + i * 1024 + ln * 16;
      region = LQT + i * 1024;
    } else if (i < 16) {
      int ii = i - 8;
      srcmat = Ktg;
      srcbyte = (unsigned)b * 8192 + ii * 1024 + ln * 16;
      region = LKT + ii * 1024;
    } else {
      int ii = i - 16;
      srcmat = Vg;
      int d = ii * 1024 + ln * 16;
      int p = d >> 9;
      int cc = d & 511;
      srcbyte = (unsigned)b * 8192 + p * 512 + (unsigned)(cc ^ ((p & 7) << 4));
      region = LVS + ii * 1024;
    }
    gload_lds16((const char*)srcmat + srcbyte, &lds[region]);
  }
  __syncthreads();

  // ---- Q B-frags (hoisted): B[k=p=g*4+j][n=e=lr] from Qt rows ----
  u32x2 qf[4];
#pragma unroll
  for (int nt = 0; nt < 4; ++nt)
    qf[nt] = *(const u32x2*)(&lds[LQT + (w * 64 + nt * 16 + lr) * 32 + g * 8]);

  u32x2 ones;
  ones.x = 0x3F803F80u; ones.y = 0x3F803F80u;

  f32x4 accT[4], dden[4];
  f32x4 z4 = {0.f, 0.f, 0.f, 0.f};
#pragma unroll
  for (int nt = 0; nt < 4; ++nt) { accT[nt] = z4; dden[nt] = z4; }

  for (int c = 0; c < 8; ++c) {
#pragma unroll
    for (int mt_ = 0; mt_ < 2; ++mt_) {
      // K A-frag: A[m=f=lr][k=p=g*4+j] from Kt rows (f = c*32 + mt_*16 + lr)
      u32x2 kf = *(const u32x2*)(&lds[LKT + (c * 32 + mt_ * 16 + lr) * 32 + g * 8]);

      // logits: S^T[f][e] ; C-layout: lane holds f = c*32+mt_*16+g*4+rg, e = w*64+nt*16+lr
      f32x4 st[4];
#pragma unroll
      for (int nt = 0; nt < 4; ++nt)
        st[nt] = mfma16(kf, qf[nt], z4);

      // V A-frag: A[m=p=lr][k=f-local=g*4+j] from V rows (swizzled cols)
      u32x2 vf = *(const u32x2*)(
          &lds[LVS + lr * 512 + ((c * 64 + mt_ * 32 + g * 8) ^ ((lr & 7) << 4))]);

      // exp -> bf16 pack: pB = B-frag [k=f-local][n=e] directly (no redistribution!)
#pragma unroll
      for (int nt = 0; nt < 4; ++nt) {
        float e0 = __expf(st[nt].x);
        float e1 = __expf(st[nt].y);
        float e2 = __expf(st[nt].z);
        float e3 = __expf(st[nt].w);
        u32x2 pB;
        pB.x = pk2(e0, e1);
        pB.y = pk2(e2, e3);
        accT[nt] = mfma16(vf, pB, accT[nt]);     // acc^T[p][e] += V^T . P
        dden[nt] = mfma16(ones, pB, dden[nt]);   // den[e] += sum_f P[f][e]
      }
    }
  }

  // ---- epilogue: lane holds acc^T[p=g*4+rg][e=w*64+nt*16+lr]; den[e] in dden[nt] ----
  size_t rowbase = (size_t)b * 4096;
#pragma unroll
  for (int nt = 0; nt < 4; ++nt) {
    int e = w * 64 + nt * 16 + lr;
    size_t col = (size_t)e * 16 + g * 4;
    float inv = 1.0f / dden[nt].x;
    f32x4 xr = *(const f32x4*)(x + rowbase + col);
    f32x4 o = accT[nt] * inv + xr;
    *(f32x4*)(out + rowbase + col) = o;
  }
}

extern "C" void kernel_launch(void* const* d_in, const int* in_sizes, int n_in,
                              void* d_out, int out_size, void* d_ws, size_t ws_size,
                              hipStream_t stream) {
  const float* x = (const float*)d_in[0];
  const float* WQ = (const float*)d_in[1];
  const float* bQ = (const float*)d_in[2];
  const float* WK = (const float*)d_in[3];
  const float* bK = (const float*)d_in[4];
  const float* WV = (const float*)d_in[5];
  const float* bV = (const float*)d_in[6];
  const float* gamma = (const float*)d_in[7];
  const float* beta = (const float*)d_in[8];
  float* out = (float*)d_out;
  char* ws = (char*)d_ws;

  float* psum = (float*)(ws);                                 // 1 MB
  float* psq = (float*)(ws + (1 << 20));                      // 1 MB
  float* An = (float*)(ws + (2 << 20));                       // 16 KB
  float* Bn = (float*)(ws + (2 << 20) + (16 << 10));          // 16 KB
  unsigned short* Qt = (unsigned short*)(ws + (size_t)(4 << 20));                 // 32 MB [b][e][p]
  unsigned short* Kt = (unsigned short*)(ws + (size_t)(4 << 20) + (32u << 20));   // 32 MB [b][f][p]
  unsigned short* Vo = (unsigned short*)(ws + (size_t)(4 << 20) + (64u << 20));   // 32 MB [b*16+p][e]

  hipLaunchKernelGGL(k_stats, dim3(256), dim3(256), 0, stream, x, psum, psq);
  hipLaunchKernelGGL(k_finalize, dim3(16), dim3(256), 0, stream, psum, psq, gamma, beta, An, Bn);
  hipLaunchKernelGGL(k_qkv, dim3(1024), dim3(256), 0, stream, x, An, Bn,
                     WQ, bQ, WK, bK, WV, bV, Qt, Kt, Vo);
  hipLaunchKernelGGL(k_attn, dim3(4096), dim3(256), 0, stream, Qt, Kt, Vo, x, out);
}